// Round 8
// baseline (900.111 us; speedup 1.0000x reference)
//
#include <hip/hip_runtime.h>
#include <stdint.h>
#include <math.h>

// Problem dims
static constexpr int BDIM = 2048;   // batch B
static constexpr int HDIM = 2048;   // hidden H
static constexpr int DDIM = 512;    // input dim D
static constexpr int NSAMP = 32;    // N_SAMPLE

// d_out layout (float elements, concatenated in return order)
static constexpr size_t OFF_H  = 0;
static constexpr size_t OFF_Z  = (size_t)BDIM * HDIM;                  // 4194304
static constexpr size_t OFF_OH = OFF_Z + (size_t)BDIM * HDIM;          // 8388608
static constexpr size_t OFF_XD = OFF_OH + (size_t)NSAMP * BDIM * HDIM; // 142606336
static constexpr size_t OFF_W  = OFF_XD + (size_t)NSAMP * BDIM * DDIM; // 176160768

// d_ws layout (float offsets): Wt fp32 [2048*512], xb bf16 [2048*512],
// Wtb bf16 [2048*512] (n-major), temp [65536]
static constexpr size_t WS_WT    = 0;                          // 1048576 floats
static constexpr size_t WS_XB    = 1048576;                    // 524288 floats (1M ushort)
static constexpr size_t WS_WTB   = WS_XB + 524288;             // 524288 floats
static constexpr size_t WS_TEMP  = WS_WTB + 524288;

typedef __attribute__((ext_vector_type(8))) short short8;
typedef __attribute__((ext_vector_type(4))) float f32x4;

__device__ __forceinline__ ushort f2bf(float f) {
  uint32_t x = __float_as_uint(f);
  return (ushort)((x + 0x7FFFu + ((x >> 16) & 1u)) >> 16);  // RNE, no NaN here
}

// ------- prep: [0,1024) transpose W -> Wt fp32 + Wtb bf16; [1024,2048) cast x
__global__ __launch_bounds__(256) void prep_kernel(const float* __restrict__ x,
                                                   ushort* __restrict__ xb,
                                                   const float* __restrict__ W,
                                                   float* __restrict__ Wt,
                                                   ushort* __restrict__ Wtb) {
  __shared__ float tile[32][33];
  if (blockIdx.x >= 1024) {
    // cast part: 1024 blocks x 256 threads x 4 floats = 1048576 elems
    const int i = ((blockIdx.x - 1024) * 256 + threadIdx.x) * 4;
    float4 v = *(const float4*)(x + i);
    ushort4 o = {f2bf(v.x), f2bf(v.y), f2bf(v.z), f2bf(v.w)};
    *(ushort4*)(xb + i) = o;
    return;
  }
  // transpose part (block-uniform branch, no divergence)
  const int tx = threadIdx.x & 31, ty = threadIdx.x >> 5;  // 32x8
  const int bx = blockIdx.x & 63;   // along H (2048/32=64)
  const int by = blockIdx.x >> 6;   // along D (512/32=16)
#pragma unroll
  for (int i = 0; i < 32; i += 8)
    tile[ty + i][tx] = W[(size_t)(by * 32 + ty + i) * HDIM + bx * 32 + tx];
  __syncthreads();
#pragma unroll
  for (int i = 0; i < 32; i += 8) {
    float v = tile[tx][ty + i];
    const size_t o = (size_t)(bx * 32 + ty + i) * DDIM + by * 32 + tx;
    Wt[o] = v;
    Wtb[o] = f2bf(v);
  }
}

// ---------------- GEMM: h = x @ W via bf16 MFMA (M=N=2048, K=512) -------------
// 64x64 tiles -> 1024 blocks = 4 blocks/CU resident. Same m92-verified
// fragment mapping: A[m=lane&15][k=(lane>>4)*8+j], C/D: col=lane&15,
// row=(lane>>4)*4+reg. (Round-7 A/B: 128^2@1blk/CU vs 64^2@4blk/CU within
// 6us -> gemm is ~25-50us, not the chain bottleneck.)
__global__ __launch_bounds__(256, 4) void gemm_mfma_kernel(const ushort* __restrict__ xb,
                                                           const ushort* __restrict__ wtb,
                                                           float* __restrict__ h) {
  __shared__ short As[64][72];  // pad 8 shorts (16B) keeps b128 align, spreads banks
  __shared__ short Bs[64][72];
  const int tid = threadIdx.x;
  const int bm = blockIdx.y * 64, bn = blockIdx.x * 64;
  const int wave = tid >> 6, lane = tid & 63;
  const int wm = (wave >> 1) * 32, wn = (wave & 1) * 32;  // 2x2 waves of 32x32
  const int lrow = lane & 15, lk = (lane >> 4) * 8;

  f32x4 acc[2][2] = {};

  const int srow = tid >> 3;         // 0..31
  const int scol = (tid & 7) * 8;    // 0..56

  for (int k0 = 0; k0 < DDIM; k0 += 64) {
#pragma unroll
    for (int p = 0; p < 2; ++p) {
      const int r = srow + p * 32;
      short8 av = *(const short8*)(xb + (size_t)(bm + r) * DDIM + k0 + scol);
      short8 bv = *(const short8*)(wtb + (size_t)(bn + r) * DDIM + k0 + scol);
      *(short8*)&As[r][scol] = av;
      *(short8*)&Bs[r][scol] = bv;
    }
    __syncthreads();
#pragma unroll
    for (int kk = 0; kk < 64; kk += 32) {
      short8 af[2], bf[2];
#pragma unroll
      for (int i = 0; i < 2; ++i) {
        af[i] = *(const short8*)&As[wm + i * 16 + lrow][kk + lk];
        bf[i] = *(const short8*)&Bs[wn + i * 16 + lrow][kk + lk];
      }
#pragma unroll
      for (int i = 0; i < 2; ++i)
#pragma unroll
        for (int j = 0; j < 2; ++j)
          acc[i][j] = __builtin_amdgcn_mfma_f32_16x16x32_bf16(af[i], bf[j], acc[i][j], 0, 0, 0);
    }
    __syncthreads();
  }
#pragma unroll
  for (int i = 0; i < 2; ++i)
#pragma unroll
    for (int j = 0; j < 2; ++j)
#pragma unroll
      for (int rg = 0; rg < 4; ++rg) {
        const int row = bm + wm + i * 16 + (lane >> 4) * 4 + rg;
        const int col = bn + wn + j * 16 + (lane & 15);
        h[(size_t)row * HDIM + col] = acc[i][j][rg];
      }
}

// ---------------- Threefry-2x32, key = (0, 42) ----------------
// rotl forced to v_alignbit_b32 (funnel shift): alignbit(x,x,32-r) == rotl(x,r)
__device__ __forceinline__ uint32_t rotl_ab(uint32_t x, int r) {
  return __builtin_amdgcn_alignbit(x, x, 32 - r);
}
__device__ __forceinline__ void threefry_0_42(uint32_t x0, uint32_t x1,
                                              uint32_t& o0, uint32_t& o1) {
  const uint32_t ks0 = 0u, ks1 = 42u, ks2 = 0x1BD11BDAu ^ 0u ^ 42u;
  x0 += ks0; x1 += ks1;
#define TF_R(r) { x0 += x1; x1 = rotl_ab(x1, (r)); x1 ^= x0; }
  TF_R(13) TF_R(15) TF_R(26) TF_R(6)   x0 += ks1; x1 += ks2 + 1u;
  TF_R(17) TF_R(29) TF_R(16) TF_R(24)  x0 += ks2; x1 += ks0 + 2u;
  TF_R(13) TF_R(15) TF_R(26) TF_R(6)   x0 += ks0; x1 += ks1 + 3u;
  TF_R(17) TF_R(29) TF_R(16) TF_R(24)  x0 += ks1; x1 += ks2 + 4u;
  TF_R(13) TF_R(15) TF_R(26) TF_R(6)   x0 += ks2; x1 += ks0 + 5u;
#undef TF_R
  o0 = x0; o1 = x1;
}

// JAX uniform(tiny,1): u = ((bits>>9)|0x3f800000) as float - 1; 0 -> tiny
__device__ __forceinline__ float bits_to_u(uint32_t bits) {
  float f = __uint_as_float((bits >> 9) | 0x3f800000u) - 1.0f;
  return (f == 0.0f) ? 1.1754943508222875e-38f : f;
}

// ---- FUSED: softmax + sample (argmax gumbel+z) + onehot + x_decoded + temp --
// One WAVE per flat sample row r = n*2048+b. NEW this round: the softmax of
// h-row b is computed IN-WAVE (val layout = hash-slot layout h = lane + k*64,
// so the rare path's z[hh] is recomputable from rmax/rinv bit-identically).
// Waves with r < 2048 write the z output row; rowDelta is now a local:
// z_max - z_min == (1 - exp(rmin-rmax)) * rinv exactly (e_max = 1).
// This deletes the softmax dispatch, one boundary drain, and the z/rowDelta
// workspace round-trips. vals[32] dies before bb[32] is born -> no VGPR
// pressure increase across the hash phase (stays under the (256,4) cap).
// Fast path (~99.9%): single screen-passer is provably the argmax.
__global__ __launch_bounds__(256, 4) void sample_fused_kernel(
    const float* __restrict__ h, const float* __restrict__ x,
    const float* __restrict__ Wt, float* __restrict__ zout,
    float* __restrict__ oh, float* __restrict__ xd, float* __restrict__ temp) {
  const int wav = threadIdx.x >> 6;
  const int lane = threadIdx.x & 63;
  const int r = blockIdx.x * 4 + wav;   // 0..65535 (flat row n*2048+b)
  const int b = r & (BDIM - 1);
  const float* hrow = h + (size_t)b * HDIM;

  // output row / x row known immediately: hoist x loads above softmax+hash so
  // HBM latency hides under ~2700 VALU cycles.
  const int j = ((r & (BDIM - 1)) << 5) | (r >> 11);
  const int c = j & (BDIM - 1);
  const f32x4* xrow = (const f32x4*)(x + (size_t)c * DDIM);
  const f32x4 xv0 = xrow[lane];
  const f32x4 xv1 = xrow[64 + lane];

  // ---- in-wave softmax over h row b (layout matches hash slots) ----
  float vals[32];
#pragma unroll
  for (int k = 0; k < 32; ++k) vals[k] = hrow[lane + (k << 6)];
  float vmax = -INFINITY, vmin = INFINITY;
#pragma unroll
  for (int k = 0; k < 32; ++k) {
    vmax = fmaxf(vmax, vals[k]);
    vmin = fminf(vmin, vals[k]);
  }
#pragma unroll
  for (int off = 32; off > 0; off >>= 1) {
    vmax = fmaxf(vmax, __shfl_xor(vmax, off, 64));
    vmin = fminf(vmin, __shfl_xor(vmin, off, 64));
  }
  const float rmax = vmax, rmin = vmin;
  float lsum = 0.f;
#pragma unroll
  for (int k = 0; k < 32; ++k) {
    vals[k] = expf(vals[k] - rmax);   // vals now holds e[k]
    lsum += vals[k];
  }
#pragma unroll
  for (int off = 32; off > 0; off >>= 1) lsum += __shfl_xor(lsum, off, 64);
  const float rinv = 1.0f / lsum;
  // conservative screen slack: true z-spread + 3e-4 pad (pad >> any ulp noise)
  const float dpad = (1.0f - expf(rmin - rmax)) * rinv + 3e-4f;

  // z output: one wave per row (r < 2048 <=> n == 0), NT scalar stores
  if ((r >> 11) == 0) {
    float* zrow = zout + (size_t)b * HDIM;
#pragma unroll
    for (int k = 0; k < 32; ++k)
      __builtin_nontemporal_store(vals[k] * rinv, &zrow[lane + (k << 6)]);
  }
  // vals[] dead from here: register allocator reuses for bb[]

  // ---- threefry phase ----
  const uint32_t base = (uint32_t)r << 11;
  uint32_t bb[32];
  uint32_t m23 = 0u;
#pragma unroll
  for (int k = 0; k < 32; ++k) {
    uint32_t o0, o1;
    threefry_0_42(0u, base + (uint32_t)(lane + (k << 6)), o0, o1);
    bb[k] = (o0 ^ o1) >> 9;
    m23 = max(m23, bb[k]);
  }
#pragma unroll
  for (int off = 32; off > 0; off >>= 1)
    m23 = max(m23, (uint32_t)__shfl_xor((int)m23, off, 64));
  const float umax = bits_to_u(m23 << 9);

  // conservative threshold: winner needs g(u) >= g(umax) - (zmax-zmin) - pad.
  // -4 ulps u-space for libm slop, then to 23-bit space (1+u has mantissa ==
  // bits>>9 exactly); m23-equality keeps row-max always in.
  float uthr = expf(-expf(-(-logf(-logf(umax)) - dpad)));
  uthr = __uint_as_float(__float_as_uint(uthr) - 4u);
  uint32_t thr23 = __float_as_uint(1.0f + uthr) & 0x7FFFFFu;
  if (thr23 > 0u) thr23 -= 1u;  // absorb 1+uthr rounding

  // per-lane candidate bitmask over the 32 k-slots
  uint32_t candMask = 0u;
#pragma unroll
  for (int k = 0; k < 32; ++k)
    if (bb[k] >= thr23 || bb[k] == m23) candMask |= (1u << k);

  // wave-total candidate count + wave-min candidate index (h = lane + k*64;
  // lowest set bit = smallest k = smallest h for this lane)
  int total = __popc(candMask);
  int myh = candMask ? (lane + ((__ffs(candMask) - 1) << 6)) : 0x7fffffff;
#pragma unroll
  for (int off = 32; off > 0; off >>= 1) {
    total += __shfl_xor(total, off, 64);
    myh = min(myh, __shfl_xor(myh, off, 64));
  }

  int bh;
  if (total == 1) {
    // single screen-passer is provably the argmax
    bh = myh;
  } else {
    // exact path (rare, wave-uniform): rank candidates by double gumbel+z.
    // z[hh] recomputed from h (bit-identical to the stored z: same expf input,
    // same rmax, same rinv multiply).
    double best = -1e300; bh = 0x7fffffff;
#pragma unroll
    for (int k = 0; k < 32; ++k) {
      if (candMask & (1u << k)) {
        const int hh = lane + (k << 6);
        const float uk = bits_to_u(bb[k] << 9);
        const float zc = expf(hrow[hh] - rmax) * rinv;
        double s = -log(-log((double)uk)) + (double)zc;
        if (s > best || (s == best && hh < bh)) { best = s; bh = hh; }
      }
    }
#pragma unroll
    for (int off = 32; off > 0; off >>= 1) {
      double so = __shfl_xor(best, off, 64);
      int ho = __shfl_xor(bh, off, 64);
      if (so > best || (so == best && ho < bh)) { best = so; bh = ho; }
    }
  }

  // ---- output row j of oh / xd / temp ----
  f32x4* ohrow = (f32x4*)(oh + (size_t)j * HDIM);
#pragma unroll
  for (int k = 0; k < 8; ++k) {
    const int idx4 = (k << 6) + lane;
    const unsigned d = (unsigned)(bh - (idx4 << 2));
    f32x4 v;
    v.x = (d == 0u) ? 1.f : 0.f;
    v.y = (d == 1u) ? 1.f : 0.f;
    v.z = (d == 2u) ? 1.f : 0.f;
    v.w = (d == 3u) ? 1.f : 0.f;
    __builtin_nontemporal_store(v, &ohrow[idx4]);
  }

  const f32x4* wrow = (const f32x4*)(Wt + (size_t)bh * DDIM);
  f32x4* xdrow = (f32x4*)(xd + (size_t)j * DDIM);
  const f32x4 wv0 = wrow[lane];
  const f32x4 wv1 = wrow[64 + lane];
  __builtin_nontemporal_store(wv0, &xdrow[lane]);
  __builtin_nontemporal_store(wv1, &xdrow[64 + lane]);
  float ss = 0.f;
  {
    const float dx = xv0.x - wv0.x, dy = xv0.y - wv0.y;
    const float dz = xv0.z - wv0.z, dw = xv0.w - wv0.w;
    ss += dx * dx + dy * dy + dz * dz + dw * dw;
  }
  {
    const float dx = xv1.x - wv1.x, dy = xv1.y - wv1.y;
    const float dz = xv1.z - wv1.z, dw = xv1.w - wv1.w;
    ss += dx * dx + dy * dy + dz * dz + dw * dw;
  }
#pragma unroll
  for (int off = 32; off > 0; off >>= 1) ss += __shfl_xor(ss, off, 64);
  if (lane == 0) temp[j] = 0.3989422804014327f * expf(-0.5f * ss);
}

// ---------------- weight = temp / mean_n(temp) ----------------
__global__ __launch_bounds__(256) void weight_kernel(const float* __restrict__ temp,
                                                     float* __restrict__ wout) {
  const int c = blockIdx.x * 256 + threadIdx.x;  // 0..2047
  if (c >= BDIM) return;
  float sum = 0.f;
#pragma unroll
  for (int a = 0; a < NSAMP; ++a) sum += temp[a * BDIM + c];
  const float mean = sum / 32.0f;
#pragma unroll
  for (int a = 0; a < NSAMP; ++a) wout[a * BDIM + c] = temp[a * BDIM + c] / mean;
}

extern "C" void kernel_launch(void* const* d_in, const int* in_sizes, int n_in,
                              void* d_out, int out_size, void* d_ws, size_t ws_size,
                              hipStream_t stream) {
  (void)in_sizes; (void)n_in; (void)out_size; (void)ws_size;
  const float* x = (const float*)d_in[0];  // [2048,512]
  const float* W = (const float*)d_in[1];  // [512,2048]
  float* out = (float*)d_out;

  float* h  = out + OFF_H;
  float* z  = out + OFF_Z;
  float* oh = out + OFF_OH;
  float* xd = out + OFF_XD;
  float* wo = out + OFF_W;

  float* ws = (float*)d_ws;
  float* Wt = ws + WS_WT;
  ushort* xb = (ushort*)(ws + WS_XB);
  ushort* Wtb = (ushort*)(ws + WS_WTB);
  float* temp = ws + WS_TEMP;

  prep_kernel<<<2048, 256, 0, stream>>>(x, xb, W, Wt, Wtb);
  gemm_mfma_kernel<<<dim3(32, 32), 256, 0, stream>>>(xb, Wtb, h);
  sample_fused_kernel<<<16384, 256, 0, stream>>>(h, x, Wt, z, oh, xd, temp);
  weight_kernel<<<8, 256, 0, stream>>>(temp, wo);
}

// Round 9
// 857.118 us; speedup vs baseline: 1.0502x; 1.0502x over previous
//
#include <hip/hip_runtime.h>
#include <stdint.h>
#include <math.h>

// Problem dims
static constexpr int BDIM = 2048;   // batch B
static constexpr int HDIM = 2048;   // hidden H
static constexpr int DDIM = 512;    // input dim D
static constexpr int NSAMP = 32;    // N_SAMPLE

// d_out layout (float elements, concatenated in return order)
static constexpr size_t OFF_H  = 0;
static constexpr size_t OFF_Z  = (size_t)BDIM * HDIM;                  // 4194304
static constexpr size_t OFF_OH = OFF_Z + (size_t)BDIM * HDIM;          // 8388608
static constexpr size_t OFF_XD = OFF_OH + (size_t)NSAMP * BDIM * HDIM; // 142606336
static constexpr size_t OFF_W  = OFF_XD + (size_t)NSAMP * BDIM * DDIM; // 176160768

// d_ws layout (float offsets): Wt fp32 [2048*512], xb bf16 [2048*512],
// Wtb bf16 [2048*512] (n-major), temp [65536], rowDelta [2048]
static constexpr size_t WS_WT    = 0;                          // 1048576 floats
static constexpr size_t WS_XB    = 1048576;                    // 524288 floats (1M ushort)
static constexpr size_t WS_WTB   = WS_XB + 524288;             // 524288 floats
static constexpr size_t WS_TEMP  = WS_WTB + 524288;
static constexpr size_t WS_DELTA = WS_TEMP + 65536;

typedef __attribute__((ext_vector_type(8))) short short8;
typedef __attribute__((ext_vector_type(4))) float f32x4;

__device__ __forceinline__ ushort f2bf(float f) {
  uint32_t x = __float_as_uint(f);
  return (ushort)((x + 0x7FFFu + ((x >> 16) & 1u)) >> 16);  // RNE, no NaN here
}

// ------- prep: [0,1024) transpose W -> Wt fp32 + Wtb bf16; [1024,2048) cast x
__global__ __launch_bounds__(256) void prep_kernel(const float* __restrict__ x,
                                                   ushort* __restrict__ xb,
                                                   const float* __restrict__ W,
                                                   float* __restrict__ Wt,
                                                   ushort* __restrict__ Wtb) {
  __shared__ float tile[32][33];
  if (blockIdx.x >= 1024) {
    // cast part: 1024 blocks x 256 threads x 4 floats = 1048576 elems
    const int i = ((blockIdx.x - 1024) * 256 + threadIdx.x) * 4;
    float4 v = *(const float4*)(x + i);
    ushort4 o = {f2bf(v.x), f2bf(v.y), f2bf(v.z), f2bf(v.w)};
    *(ushort4*)(xb + i) = o;
    return;
  }
  // transpose part (block-uniform branch, no divergence)
  const int tx = threadIdx.x & 31, ty = threadIdx.x >> 5;  // 32x8
  const int bx = blockIdx.x & 63;   // along H (2048/32=64)
  const int by = blockIdx.x >> 6;   // along D (512/32=16)
#pragma unroll
  for (int i = 0; i < 32; i += 8)
    tile[ty + i][tx] = W[(size_t)(by * 32 + ty + i) * HDIM + bx * 32 + tx];
  __syncthreads();
#pragma unroll
  for (int i = 0; i < 32; i += 8) {
    float v = tile[tx][ty + i];
    const size_t o = (size_t)(bx * 32 + ty + i) * DDIM + by * 32 + tx;
    Wt[o] = v;
    Wtb[o] = f2bf(v);
  }
}

// ---------------- GEMM: h = x @ W via bf16 MFMA, LDS-FREE (M=N=2048, K=512) --
// Round-8 calibration (sampler VALU-bound +60 for added softmax) implies the
// old LDS-staged gemm was ~120-170us: at 64^2 tiles its ratio was 4 MFMA per
// {2 barriers + 4 global loads + 8 ds_reads}; at 128^2/1blk-per-CU the barrier
// drains were fully exposed (round-7 A/B: both equally slow).
// Here: operands are L2-resident (xb+wtb = 4MB), so read fragments STRAIGHT
// from global. Zero LDS, zero __syncthreads. Same m92-verified fragment
// indices as the LDS version (A[m=lane&15][k=(lane>>4)*8+j], C/D col=lane&15,
// row=(lane>>4)*4+reg) -- only the data path changed.
// 64x64 tile, grid 32x32=1024 blocks = 4 blocks/CU = 16 waves/CU; per wave
// 64 short8 loads + 64 MFMA, loads pipelined by the compiler, latency hidden
// by TLP. Coalescing: lanes l,l+16,l+32,l+48 read the same row's 64B span.
__global__ __launch_bounds__(256, 4) void gemm_mfma_kernel(const ushort* __restrict__ xb,
                                                           const ushort* __restrict__ wtb,
                                                           float* __restrict__ h) {
  const int tid = threadIdx.x;
  const int bm = blockIdx.y * 64, bn = blockIdx.x * 64;
  const int wave = tid >> 6, lane = tid & 63;
  const int wm = (wave >> 1) * 32, wn = (wave & 1) * 32;  // 2x2 waves of 32x32
  const int lrow = lane & 15, lk = (lane >> 4) * 8;

  const ushort* a0p = xb + (size_t)(bm + wm + lrow) * DDIM + lk;
  const ushort* a1p = a0p + (size_t)16 * DDIM;
  const ushort* b0p = wtb + (size_t)(bn + wn + lrow) * DDIM + lk;
  const ushort* b1p = b0p + (size_t)16 * DDIM;

  f32x4 acc[2][2] = {};
#pragma unroll
  for (int k0 = 0; k0 < DDIM; k0 += 32) {
    const short8 a0 = *(const short8*)(a0p + k0);
    const short8 a1 = *(const short8*)(a1p + k0);
    const short8 b0 = *(const short8*)(b0p + k0);
    const short8 b1 = *(const short8*)(b1p + k0);
    acc[0][0] = __builtin_amdgcn_mfma_f32_16x16x32_bf16(a0, b0, acc[0][0], 0, 0, 0);
    acc[0][1] = __builtin_amdgcn_mfma_f32_16x16x32_bf16(a0, b1, acc[0][1], 0, 0, 0);
    acc[1][0] = __builtin_amdgcn_mfma_f32_16x16x32_bf16(a1, b0, acc[1][0], 0, 0, 0);
    acc[1][1] = __builtin_amdgcn_mfma_f32_16x16x32_bf16(a1, b1, acc[1][1], 0, 0, 0);
  }
#pragma unroll
  for (int i = 0; i < 2; ++i)
#pragma unroll
    for (int j = 0; j < 2; ++j)
#pragma unroll
      for (int rg = 0; rg < 4; ++rg) {
        const int row = bm + wm + i * 16 + (lane >> 4) * 4 + rg;
        const int col = bn + wn + j * 16 + (lane & 15);
        h[(size_t)row * HDIM + col] = acc[i][j][rg];
      }
}

// ---------------- Softmax rows + per-row z-spread (wave-shuffle, float4 I/O) --
__global__ __launch_bounds__(256) void softmax_kernel(const float* __restrict__ h,
                                                      float* __restrict__ z,
                                                      float* __restrict__ rowDelta) {
  const int b = blockIdx.x;
  const int tid = threadIdx.x;
  const int lane = tid & 63, wav = tid >> 6;
  const float* row = h + (size_t)b * HDIM;
  float* zrow = z + (size_t)b * HDIM;
  __shared__ float wmaxs[4], wmins[4], wsums[4];

  // each thread owns 8 contiguous floats -> 2 float4 loads, 32B/lane coalesced
  const float4 v0 = ((const float4*)row)[tid * 2];
  const float4 v1 = ((const float4*)row)[tid * 2 + 1];
  float vals[8] = {v0.x, v0.y, v0.z, v0.w, v1.x, v1.y, v1.z, v1.w};
  float vmax = -INFINITY, vmin = INFINITY;
#pragma unroll
  for (int k = 0; k < 8; ++k) {
    vmax = fmaxf(vmax, vals[k]);
    vmin = fminf(vmin, vals[k]);
  }
#pragma unroll
  for (int off = 32; off > 0; off >>= 1) {
    vmax = fmaxf(vmax, __shfl_xor(vmax, off, 64));
    vmin = fminf(vmin, __shfl_xor(vmin, off, 64));
  }
  if (lane == 0) { wmaxs[wav] = vmax; wmins[wav] = vmin; }
  __syncthreads();
  const float rmax = fmaxf(fmaxf(wmaxs[0], wmaxs[1]), fmaxf(wmaxs[2], wmaxs[3]));
  const float rmin = fminf(fminf(wmins[0], wmins[1]), fminf(wmins[2], wmins[3]));

  float e[8];
  float lsum = 0.f;
#pragma unroll
  for (int k = 0; k < 8; ++k) {
    e[k] = expf(vals[k] - rmax);
    lsum += e[k];
  }
#pragma unroll
  for (int off = 32; off > 0; off >>= 1) lsum += __shfl_xor(lsum, off, 64);
  if (lane == 0) wsums[wav] = lsum;
  __syncthreads();
  const float rsum = wsums[0] + wsums[1] + wsums[2] + wsums[3];
  const float rinv = 1.0f / rsum;
  float4 o0 = {e[0] * rinv, e[1] * rinv, e[2] * rinv, e[3] * rinv};
  float4 o1 = {e[4] * rinv, e[5] * rinv, e[6] * rinv, e[7] * rinv};
  ((float4*)zrow)[tid * 2] = o0;
  ((float4*)zrow)[tid * 2 + 1] = o1;
  if (tid == 0) rowDelta[b] = (1.0f - expf(rmin - rmax)) / rsum;  // z_max - z_min
}

// ---------------- Threefry-2x32, key = (0, 42) ----------------
// rotl forced to v_alignbit_b32 (funnel shift): alignbit(x,x,32-r) == rotl(x,r)
__device__ __forceinline__ uint32_t rotl_ab(uint32_t x, int r) {
  return __builtin_amdgcn_alignbit(x, x, 32 - r);
}
__device__ __forceinline__ void threefry_0_42(uint32_t x0, uint32_t x1,
                                              uint32_t& o0, uint32_t& o1) {
  const uint32_t ks0 = 0u, ks1 = 42u, ks2 = 0x1BD11BDAu ^ 0u ^ 42u;
  x0 += ks0; x1 += ks1;
#define TF_R(r) { x0 += x1; x1 = rotl_ab(x1, (r)); x1 ^= x0; }
  TF_R(13) TF_R(15) TF_R(26) TF_R(6)   x0 += ks1; x1 += ks2 + 1u;
  TF_R(17) TF_R(29) TF_R(16) TF_R(24)  x0 += ks2; x1 += ks0 + 2u;
  TF_R(13) TF_R(15) TF_R(26) TF_R(6)   x0 += ks0; x1 += ks1 + 3u;
  TF_R(17) TF_R(29) TF_R(16) TF_R(24)  x0 += ks1; x1 += ks2 + 4u;
  TF_R(13) TF_R(15) TF_R(26) TF_R(6)   x0 += ks2; x1 += ks0 + 5u;
#undef TF_R
  o0 = x0; o1 = x1;
}

// JAX uniform(tiny,1): u = ((bits>>9)|0x3f800000) as float - 1; 0 -> tiny
__device__ __forceinline__ float bits_to_u(uint32_t bits) {
  float f = __uint_as_float((bits >> 9) | 0x3f800000u) - 1.0f;
  return (f == 0.0f) ? 1.1754943508222875e-38f : f;
}

// ---- FUSED: sample (argmax gumbel+z) + onehot row + x_decoded row + temp ----
// One WAVE per flat sample row r = n*2048+b; 32 hashes/lane (bb[32] in regs).
// REVERTED to the round-7 form (840us): round-8's in-sampler softmax was 32x
// redundant work in a VALU-issue-bound kernel (+60us, theory falsified).
// The 23-bit screen is ~2-4 ulps below the row max -> E[candidates] ~ 1.001.
// FAST PATH (~99.9% of waves): single screen-passer is provably the argmax.
// Output rows (j = scramble inverse): oh (NT), xd (NT), temp.
__global__ __launch_bounds__(256, 4) void sample_fused_kernel(
    const float* __restrict__ z, const float* __restrict__ rowDelta,
    const float* __restrict__ x, const float* __restrict__ Wt,
    float* __restrict__ oh, float* __restrict__ xd, float* __restrict__ temp) {
  const int wav = threadIdx.x >> 6;
  const int lane = threadIdx.x & 63;
  const int r = blockIdx.x * 4 + wav;   // 0..65535 (flat row n*2048+b)
  const int b = r & (BDIM - 1);
  const float* zrow = z + (size_t)b * HDIM;

  // output row / x row known immediately: hoist x loads + rowDelta above the
  // threefry phase so HBM latency hides under ~2400 VALU cycles of hashing.
  const int j = ((r & (BDIM - 1)) << 5) | (r >> 11);
  const int c = j & (BDIM - 1);
  const f32x4* xrow = (const f32x4*)(x + (size_t)c * DDIM);
  const f32x4 xv0 = xrow[lane];
  const f32x4 xv1 = xrow[64 + lane];
  const float dpad0 = rowDelta[b];

  const uint32_t base = (uint32_t)r << 11;
  uint32_t bb[32];
  uint32_t m23 = 0u;
#pragma unroll
  for (int k = 0; k < 32; ++k) {
    uint32_t o0, o1;
    threefry_0_42(0u, base + (uint32_t)(lane + (k << 6)), o0, o1);
    bb[k] = (o0 ^ o1) >> 9;
    m23 = max(m23, bb[k]);
  }
#pragma unroll
  for (int off = 32; off > 0; off >>= 1)
    m23 = max(m23, (uint32_t)__shfl_xor((int)m23, off, 64));
  const float umax = bits_to_u(m23 << 9);

  // conservative threshold: winner needs g(u) >= g(umax) - (zmax-zmin) - pad.
  // pad 3e-4 in g-space, -4 ulps u-space for libm slop, then to 23-bit space
  // (1+u has mantissa == bits>>9 exactly); m23-equality keeps row-max always in.
  const float dpad = dpad0 + 3e-4f;
  float uthr = expf(-expf(-(-logf(-logf(umax)) - dpad)));
  uthr = __uint_as_float(__float_as_uint(uthr) - 4u);
  uint32_t thr23 = __float_as_uint(1.0f + uthr) & 0x7FFFFFu;
  if (thr23 > 0u) thr23 -= 1u;  // absorb 1+uthr rounding

  // per-lane candidate bitmask over the 32 k-slots
  uint32_t candMask = 0u;
#pragma unroll
  for (int k = 0; k < 32; ++k)
    if (bb[k] >= thr23 || bb[k] == m23) candMask |= (1u << k);

  // wave-total candidate count + wave-min candidate index (h = lane + k*64;
  // lowest set bit = smallest k = smallest h for this lane)
  int total = __popc(candMask);
  int myh = candMask ? (lane + ((__ffs(candMask) - 1) << 6)) : 0x7fffffff;
#pragma unroll
  for (int off = 32; off > 0; off >>= 1) {
    total += __shfl_xor(total, off, 64);
    myh = min(myh, __shfl_xor(myh, off, 64));
  }

  int bh;
  if (total == 1) {
    // single screen-passer is provably the argmax
    bh = myh;
  } else {
    // exact path (rare, wave-uniform): rank candidates by double gumbel+z
    double best = -1e300; bh = 0x7fffffff;
#pragma unroll
    for (int k = 0; k < 32; ++k) {
      if (candMask & (1u << k)) {
        const int hh = lane + (k << 6);
        const float uk = bits_to_u(bb[k] << 9);
        double s = -log(-log((double)uk)) + (double)zrow[hh];
        if (s > best || (s == best && hh < bh)) { best = s; bh = hh; }
      }
    }
#pragma unroll
    for (int off = 32; off > 0; off >>= 1) {
      double so = __shfl_xor(best, off, 64);
      int ho = __shfl_xor(bh, off, 64);
      if (so > best || (so == best && ho < bh)) { best = so; bh = ho; }
    }
  }

  // ---- output row j of oh / xd / temp ----
  f32x4* ohrow = (f32x4*)(oh + (size_t)j * HDIM);
#pragma unroll
  for (int k = 0; k < 8; ++k) {
    const int idx4 = (k << 6) + lane;
    const unsigned d = (unsigned)(bh - (idx4 << 2));
    f32x4 v;
    v.x = (d == 0u) ? 1.f : 0.f;
    v.y = (d == 1u) ? 1.f : 0.f;
    v.z = (d == 2u) ? 1.f : 0.f;
    v.w = (d == 3u) ? 1.f : 0.f;
    __builtin_nontemporal_store(v, &ohrow[idx4]);
  }

  const f32x4* wrow = (const f32x4*)(Wt + (size_t)bh * DDIM);
  f32x4* xdrow = (f32x4*)(xd + (size_t)j * DDIM);
  const f32x4 wv0 = wrow[lane];
  const f32x4 wv1 = wrow[64 + lane];
  __builtin_nontemporal_store(wv0, &xdrow[lane]);
  __builtin_nontemporal_store(wv1, &xdrow[64 + lane]);
  float ss = 0.f;
  {
    const float dx = xv0.x - wv0.x, dy = xv0.y - wv0.y;
    const float dz = xv0.z - wv0.z, dw = xv0.w - wv0.w;
    ss += dx * dx + dy * dy + dz * dz + dw * dw;
  }
  {
    const float dx = xv1.x - wv1.x, dy = xv1.y - wv1.y;
    const float dz = xv1.z - wv1.z, dw = xv1.w - wv1.w;
    ss += dx * dx + dy * dy + dz * dz + dw * dw;
  }
#pragma unroll
  for (int off = 32; off > 0; off >>= 1) ss += __shfl_xor(ss, off, 64);
  if (lane == 0) temp[j] = 0.3989422804014327f * expf(-0.5f * ss);
}

// ---------------- weight = temp / mean_n(temp) ----------------
__global__ __launch_bounds__(256) void weight_kernel(const float* __restrict__ temp,
                                                     float* __restrict__ wout) {
  const int c = blockIdx.x * 256 + threadIdx.x;  // 0..2047
  if (c >= BDIM) return;
  float sum = 0.f;
#pragma unroll
  for (int a = 0; a < NSAMP; ++a) sum += temp[a * BDIM + c];
  const float mean = sum / 32.0f;
#pragma unroll
  for (int a = 0; a < NSAMP; ++a) wout[a * BDIM + c] = temp[a * BDIM + c] / mean;
}

extern "C" void kernel_launch(void* const* d_in, const int* in_sizes, int n_in,
                              void* d_out, int out_size, void* d_ws, size_t ws_size,
                              hipStream_t stream) {
  (void)in_sizes; (void)n_in; (void)out_size; (void)ws_size;
  const float* x = (const float*)d_in[0];  // [2048,512]
  const float* W = (const float*)d_in[1];  // [512,2048]
  float* out = (float*)d_out;

  float* h  = out + OFF_H;
  float* z  = out + OFF_Z;
  float* oh = out + OFF_OH;
  float* xd = out + OFF_XD;
  float* wo = out + OFF_W;

  float* ws = (float*)d_ws;
  float* Wt = ws + WS_WT;
  ushort* xb = (ushort*)(ws + WS_XB);
  ushort* Wtb = (ushort*)(ws + WS_WTB);
  float* temp = ws + WS_TEMP;
  float* rowDelta = ws + WS_DELTA;

  prep_kernel<<<2048, 256, 0, stream>>>(x, xb, W, Wt, Wtb);
  gemm_mfma_kernel<<<dim3(32, 32), 256, 0, stream>>>(xb, Wtb, h);
  softmax_kernel<<<2048, 256, 0, stream>>>(h, z, rowDelta);
  sample_fused_kernel<<<16384, 256, 0, stream>>>(z, rowDelta, x, Wt, oh, xd, temp);
  weight_kernel<<<8, 256, 0, stream>>>(temp, wo);
}

// Round 10
// 837.207 us; speedup vs baseline: 1.0751x; 1.0238x over previous
//
#include <hip/hip_runtime.h>
#include <stdint.h>
#include <math.h>

// Problem dims
static constexpr int BDIM = 2048;   // batch B
static constexpr int HDIM = 2048;   // hidden H
static constexpr int DDIM = 512;    // input dim D
static constexpr int NSAMP = 32;    // N_SAMPLE

// d_out layout (float elements, concatenated in return order)
static constexpr size_t OFF_H  = 0;
static constexpr size_t OFF_Z  = (size_t)BDIM * HDIM;                  // 4194304
static constexpr size_t OFF_OH = OFF_Z + (size_t)BDIM * HDIM;          // 8388608
static constexpr size_t OFF_XD = OFF_OH + (size_t)NSAMP * BDIM * HDIM; // 142606336
static constexpr size_t OFF_W  = OFF_XD + (size_t)NSAMP * BDIM * DDIM; // 176160768

// d_ws layout (float offsets): Wt fp32 [2048*512], xb bf16 [2048*512],
// Wtb bf16 [2048*512] (n-major), temp [65536], rowDelta [2048]
static constexpr size_t WS_WT    = 0;                          // 1048576 floats
static constexpr size_t WS_XB    = 1048576;                    // 524288 floats (1M ushort)
static constexpr size_t WS_WTB   = WS_XB + 524288;             // 524288 floats
static constexpr size_t WS_TEMP  = WS_WTB + 524288;
static constexpr size_t WS_DELTA = WS_TEMP + 65536;

typedef __attribute__((ext_vector_type(8))) short short8;
typedef __attribute__((ext_vector_type(4))) float f32x4;

__device__ __forceinline__ ushort f2bf(float f) {
  uint32_t x = __float_as_uint(f);
  return (ushort)((x + 0x7FFFu + ((x >> 16) & 1u)) >> 16);  // RNE, no NaN here
}

// ------- prep: [0,1024) transpose W -> Wt fp32 + Wtb bf16; [1024,2048) cast x
__global__ __launch_bounds__(256) void prep_kernel(const float* __restrict__ x,
                                                   ushort* __restrict__ xb,
                                                   const float* __restrict__ W,
                                                   float* __restrict__ Wt,
                                                   ushort* __restrict__ Wtb) {
  __shared__ float tile[32][33];
  if (blockIdx.x >= 1024) {
    // cast part: 1024 blocks x 256 threads x 4 floats = 1048576 elems
    const int i = ((blockIdx.x - 1024) * 256 + threadIdx.x) * 4;
    float4 v = *(const float4*)(x + i);
    ushort4 o = {f2bf(v.x), f2bf(v.y), f2bf(v.z), f2bf(v.w)};
    *(ushort4*)(xb + i) = o;
    return;
  }
  // transpose part (block-uniform branch, no divergence)
  const int tx = threadIdx.x & 31, ty = threadIdx.x >> 5;  // 32x8
  const int bx = blockIdx.x & 63;   // along H (2048/32=64)
  const int by = blockIdx.x >> 6;   // along D (512/32=16)
#pragma unroll
  for (int i = 0; i < 32; i += 8)
    tile[ty + i][tx] = W[(size_t)(by * 32 + ty + i) * HDIM + bx * 32 + tx];
  __syncthreads();
#pragma unroll
  for (int i = 0; i < 32; i += 8) {
    float v = tile[tx][ty + i];
    const size_t o = (size_t)(bx * 32 + ty + i) * DDIM + by * 32 + tx;
    Wt[o] = v;
    Wtb[o] = f2bf(v);
  }
}

// ---------------- GEMM: h = x @ W via bf16 MFMA (M=N=2048, K=512) -------------
// ROUND-7 VERSION (session best 840.1us). Round-9 A/B: LDS-free was +17us
// (4x VMEM issue per MFMA); 128^2@1blk/CU was +6us. All variants 840-857 ->
// gemm is ~10-40us, NOT the chain bottleneck. 64x64 tiles, 4 blocks/CU.
// m92-verified fragment mapping: A[m=lane&15][k=(lane>>4)*8+j],
// C/D: col=lane&15, row=(lane>>4)*4+reg.
__global__ __launch_bounds__(256, 4) void gemm_mfma_kernel(const ushort* __restrict__ xb,
                                                           const ushort* __restrict__ wtb,
                                                           float* __restrict__ h) {
  __shared__ short As[64][72];  // pad 8 shorts (16B) keeps b128 align, spreads banks
  __shared__ short Bs[64][72];
  const int tid = threadIdx.x;
  const int bm = blockIdx.y * 64, bn = blockIdx.x * 64;
  const int wave = tid >> 6, lane = tid & 63;
  const int wm = (wave >> 1) * 32, wn = (wave & 1) * 32;  // 2x2 waves of 32x32
  const int lrow = lane & 15, lk = (lane >> 4) * 8;

  f32x4 acc[2][2] = {};

  const int srow = tid >> 3;         // 0..31
  const int scol = (tid & 7) * 8;    // 0..56

  for (int k0 = 0; k0 < DDIM; k0 += 64) {
#pragma unroll
    for (int p = 0; p < 2; ++p) {
      const int r = srow + p * 32;
      short8 av = *(const short8*)(xb + (size_t)(bm + r) * DDIM + k0 + scol);
      short8 bv = *(const short8*)(wtb + (size_t)(bn + r) * DDIM + k0 + scol);
      *(short8*)&As[r][scol] = av;
      *(short8*)&Bs[r][scol] = bv;
    }
    __syncthreads();
#pragma unroll
    for (int kk = 0; kk < 64; kk += 32) {
      short8 af[2], bf[2];
#pragma unroll
      for (int i = 0; i < 2; ++i) {
        af[i] = *(const short8*)&As[wm + i * 16 + lrow][kk + lk];
        bf[i] = *(const short8*)&Bs[wn + i * 16 + lrow][kk + lk];
      }
#pragma unroll
      for (int i = 0; i < 2; ++i)
#pragma unroll
        for (int j = 0; j < 2; ++j)
          acc[i][j] = __builtin_amdgcn_mfma_f32_16x16x32_bf16(af[i], bf[j], acc[i][j], 0, 0, 0);
    }
    __syncthreads();
  }
#pragma unroll
  for (int i = 0; i < 2; ++i)
#pragma unroll
    for (int j = 0; j < 2; ++j)
#pragma unroll
      for (int rg = 0; rg < 4; ++rg) {
        const int row = bm + wm + i * 16 + (lane >> 4) * 4 + rg;
        const int col = bn + wn + j * 16 + (lane & 15);
        h[(size_t)row * HDIM + col] = acc[i][j][rg];
      }
}

// ---------------- Softmax rows + per-row z-spread (wave-shuffle, float4 I/O) --
__global__ __launch_bounds__(256) void softmax_kernel(const float* __restrict__ h,
                                                      float* __restrict__ z,
                                                      float* __restrict__ rowDelta) {
  const int b = blockIdx.x;
  const int tid = threadIdx.x;
  const int lane = tid & 63, wav = tid >> 6;
  const float* row = h + (size_t)b * HDIM;
  float* zrow = z + (size_t)b * HDIM;
  __shared__ float wmaxs[4], wmins[4], wsums[4];

  // each thread owns 8 contiguous floats -> 2 float4 loads, 32B/lane coalesced
  const float4 v0 = ((const float4*)row)[tid * 2];
  const float4 v1 = ((const float4*)row)[tid * 2 + 1];
  float vals[8] = {v0.x, v0.y, v0.z, v0.w, v1.x, v1.y, v1.z, v1.w};
  float vmax = -INFINITY, vmin = INFINITY;
#pragma unroll
  for (int k = 0; k < 8; ++k) {
    vmax = fmaxf(vmax, vals[k]);
    vmin = fminf(vmin, vals[k]);
  }
#pragma unroll
  for (int off = 32; off > 0; off >>= 1) {
    vmax = fmaxf(vmax, __shfl_xor(vmax, off, 64));
    vmin = fminf(vmin, __shfl_xor(vmin, off, 64));
  }
  if (lane == 0) { wmaxs[wav] = vmax; wmins[wav] = vmin; }
  __syncthreads();
  const float rmax = fmaxf(fmaxf(wmaxs[0], wmaxs[1]), fmaxf(wmaxs[2], wmaxs[3]));
  const float rmin = fminf(fminf(wmins[0], wmins[1]), fminf(wmins[2], wmins[3]));

  float e[8];
  float lsum = 0.f;
#pragma unroll
  for (int k = 0; k < 8; ++k) {
    e[k] = expf(vals[k] - rmax);
    lsum += e[k];
  }
#pragma unroll
  for (int off = 32; off > 0; off >>= 1) lsum += __shfl_xor(lsum, off, 64);
  if (lane == 0) wsums[wav] = lsum;
  __syncthreads();
  const float rsum = wsums[0] + wsums[1] + wsums[2] + wsums[3];
  const float rinv = 1.0f / rsum;
  float4 o0 = {e[0] * rinv, e[1] * rinv, e[2] * rinv, e[3] * rinv};
  float4 o1 = {e[4] * rinv, e[5] * rinv, e[6] * rinv, e[7] * rinv};
  ((float4*)zrow)[tid * 2] = o0;
  ((float4*)zrow)[tid * 2 + 1] = o1;
  if (tid == 0) rowDelta[b] = (1.0f - expf(rmin - rmax)) / rsum;  // z_max - z_min
}

// ---------------- Threefry-2x32, key = (0, 42) ----------------
// rotl forced to v_alignbit_b32 (funnel shift): alignbit(x,x,32-r) == rotl(x,r)
__device__ __forceinline__ uint32_t rotl_ab(uint32_t x, int r) {
  return __builtin_amdgcn_alignbit(x, x, 32 - r);
}
__device__ __forceinline__ void threefry_0_42(uint32_t x0, uint32_t x1,
                                              uint32_t& o0, uint32_t& o1) {
  const uint32_t ks0 = 0u, ks1 = 42u, ks2 = 0x1BD11BDAu ^ 0u ^ 42u;
  x0 += ks0; x1 += ks1;
#define TF_R(r) { x0 += x1; x1 = rotl_ab(x1, (r)); x1 ^= x0; }
  TF_R(13) TF_R(15) TF_R(26) TF_R(6)   x0 += ks1; x1 += ks2 + 1u;
  TF_R(17) TF_R(29) TF_R(16) TF_R(24)  x0 += ks2; x1 += ks0 + 2u;
  TF_R(13) TF_R(15) TF_R(26) TF_R(6)   x0 += ks0; x1 += ks1 + 3u;
  TF_R(17) TF_R(29) TF_R(16) TF_R(24)  x0 += ks1; x1 += ks2 + 4u;
  TF_R(13) TF_R(15) TF_R(26) TF_R(6)   x0 += ks2; x1 += ks0 + 5u;
#undef TF_R
  o0 = x0; o1 = x1;
}

// JAX uniform(tiny,1): u = ((bits>>9)|0x3f800000) as float - 1; 0 -> tiny
__device__ __forceinline__ float bits_to_u(uint32_t bits) {
  float f = __uint_as_float((bits >> 9) | 0x3f800000u) - 1.0f;
  return (f == 0.0f) ? 1.1754943508222875e-38f : f;
}

// ---- FUSED: sample (argmax gumbel+z) + onehot row + x_decoded row + temp ----
// One WAVE per flat sample row r = n*2048+b; 32 hashes/lane (bb[32] in regs).
// THIS ROUND: occupancy 4 -> 6 waves/SIMD (launch_bounds(256,6), VGPR<=85).
// Budget analysis says the sampler runs ~2.4x its 136us VALU-issue floor; the
// latency tails (24 ds-permute shuffles ~40cy each + 8KB store drain ~800cy
// holding the wave slot at endpgm) are exposed at only 4 resident waves/SIMD.
// To fit 85 VGPR the x-row loads are DEFERRED until after the argmax (hash-
// phase live set ~55: bb[32]+hash temps+indices); their L2 latency then hides
// under the oh-store issue. Fast path (~99.9%): single screen-passer is
// provably the argmax (23-bit screen ~2-4 ulps below row max).
__global__ __launch_bounds__(256, 6) void sample_fused_kernel(
    const float* __restrict__ z, const float* __restrict__ rowDelta,
    const float* __restrict__ x, const float* __restrict__ Wt,
    float* __restrict__ oh, float* __restrict__ xd, float* __restrict__ temp) {
  const int wav = threadIdx.x >> 6;
  const int lane = threadIdx.x & 63;
  const int r = blockIdx.x * 4 + wav;   // 0..65535 (flat row n*2048+b)
  const int b = r & (BDIM - 1);
  const float dpad0 = rowDelta[b];      // 4B/wave, loaded early (1 reg)

  const uint32_t base = (uint32_t)r << 11;
  uint32_t bb[32];
  uint32_t m23 = 0u;
#pragma unroll
  for (int k = 0; k < 32; ++k) {
    uint32_t o0, o1;
    threefry_0_42(0u, base + (uint32_t)(lane + (k << 6)), o0, o1);
    bb[k] = (o0 ^ o1) >> 9;
    m23 = max(m23, bb[k]);
  }
#pragma unroll
  for (int off = 32; off > 0; off >>= 1)
    m23 = max(m23, (uint32_t)__shfl_xor((int)m23, off, 64));
  const float umax = bits_to_u(m23 << 9);

  // conservative threshold: winner needs g(u) >= g(umax) - (zmax-zmin) - pad.
  // pad 3e-4 in g-space, -4 ulps u-space for libm slop, then to 23-bit space
  // (1+u has mantissa == bits>>9 exactly); m23-equality keeps row-max always in.
  const float dpad = dpad0 + 3e-4f;
  float uthr = expf(-expf(-(-logf(-logf(umax)) - dpad)));
  uthr = __uint_as_float(__float_as_uint(uthr) - 4u);
  uint32_t thr23 = __float_as_uint(1.0f + uthr) & 0x7FFFFFu;
  if (thr23 > 0u) thr23 -= 1u;  // absorb 1+uthr rounding

  // per-lane candidate bitmask over the 32 k-slots
  uint32_t candMask = 0u;
#pragma unroll
  for (int k = 0; k < 32; ++k)
    if (bb[k] >= thr23 || bb[k] == m23) candMask |= (1u << k);

  // wave-total candidate count + wave-min candidate index (h = lane + k*64;
  // lowest set bit = smallest k = smallest h for this lane)
  int total = __popc(candMask);
  int myh = candMask ? (lane + ((__ffs(candMask) - 1) << 6)) : 0x7fffffff;
#pragma unroll
  for (int off = 32; off > 0; off >>= 1) {
    total += __shfl_xor(total, off, 64);
    myh = min(myh, __shfl_xor(myh, off, 64));
  }

  int bh;
  if (total == 1) {
    // single screen-passer is provably the argmax
    bh = myh;
  } else {
    // exact path (rare, wave-uniform): rank candidates by double gumbel+z
    const float* zrow = z + (size_t)b * HDIM;
    double best = -1e300; bh = 0x7fffffff;
#pragma unroll
    for (int k = 0; k < 32; ++k) {
      if (candMask & (1u << k)) {
        const int hh = lane + (k << 6);
        const float uk = bits_to_u(bb[k] << 9);
        double s = -log(-log((double)uk)) + (double)zrow[hh];
        if (s > best || (s == best && hh < bh)) { best = s; bh = hh; }
      }
    }
#pragma unroll
    for (int off = 32; off > 0; off >>= 1) {
      double so = __shfl_xor(best, off, 64);
      int ho = __shfl_xor(bh, off, 64);
      if (so > best || (so == best && ho < bh)) { best = so; bh = ho; }
    }
  }

  // ---- output row j of oh / xd / temp (j = scramble inverse) ----
  const int j = ((r & (BDIM - 1)) << 5) | (r >> 11);
  const int c = j & (BDIM - 1);  // x row for the gauss kernel

  // issue Wt/x loads FIRST (L2/L3-resident, ~200-900cy) so their latency
  // hides under the 8 oh-store iterations below.
  const f32x4* wrow = (const f32x4*)(Wt + (size_t)bh * DDIM);
  const f32x4* xrow = (const f32x4*)(x + (size_t)c * DDIM);
  const f32x4 wv0 = wrow[lane];
  const f32x4 wv1 = wrow[64 + lane];
  const f32x4 xv0 = xrow[lane];
  const f32x4 xv1 = xrow[64 + lane];

  f32x4* ohrow = (f32x4*)(oh + (size_t)j * HDIM);
#pragma unroll
  for (int k = 0; k < 8; ++k) {
    const int idx4 = (k << 6) + lane;
    const unsigned d = (unsigned)(bh - (idx4 << 2));
    f32x4 v;
    v.x = (d == 0u) ? 1.f : 0.f;
    v.y = (d == 1u) ? 1.f : 0.f;
    v.z = (d == 2u) ? 1.f : 0.f;
    v.w = (d == 3u) ? 1.f : 0.f;
    __builtin_nontemporal_store(v, &ohrow[idx4]);
  }

  f32x4* xdrow = (f32x4*)(xd + (size_t)j * DDIM);
  __builtin_nontemporal_store(wv0, &xdrow[lane]);
  __builtin_nontemporal_store(wv1, &xdrow[64 + lane]);
  float ss = 0.f;
  {
    const float dx = xv0.x - wv0.x, dy = xv0.y - wv0.y;
    const float dz = xv0.z - wv0.z, dw = xv0.w - wv0.w;
    ss += dx * dx + dy * dy + dz * dz + dw * dw;
  }
  {
    const float dx = xv1.x - wv1.x, dy = xv1.y - wv1.y;
    const float dz = xv1.z - wv1.z, dw = xv1.w - wv1.w;
    ss += dx * dx + dy * dy + dz * dz + dw * dw;
  }
#pragma unroll
  for (int off = 32; off > 0; off >>= 1) ss += __shfl_xor(ss, off, 64);
  if (lane == 0) temp[j] = 0.3989422804014327f * expf(-0.5f * ss);
}

// ---------------- weight = temp / mean_n(temp) ----------------
__global__ __launch_bounds__(256) void weight_kernel(const float* __restrict__ temp,
                                                     float* __restrict__ wout) {
  const int c = blockIdx.x * 256 + threadIdx.x;  // 0..2047
  if (c >= BDIM) return;
  float sum = 0.f;
#pragma unroll
  for (int a = 0; a < NSAMP; ++a) sum += temp[a * BDIM + c];
  const float mean = sum / 32.0f;
#pragma unroll
  for (int a = 0; a < NSAMP; ++a) wout[a * BDIM + c] = temp[a * BDIM + c] / mean;
}

extern "C" void kernel_launch(void* const* d_in, const int* in_sizes, int n_in,
                              void* d_out, int out_size, void* d_ws, size_t ws_size,
                              hipStream_t stream) {
  (void)in_sizes; (void)n_in; (void)out_size; (void)ws_size;
  const float* x = (const float*)d_in[0];  // [2048,512]
  const float* W = (const float*)d_in[1];  // [512,2048]
  float* out = (float*)d_out;

  float* h  = out + OFF_H;
  float* z  = out + OFF_Z;
  float* oh = out + OFF_OH;
  float* xd = out + OFF_XD;
  float* wo = out + OFF_W;

  float* ws = (float*)d_ws;
  float* Wt = ws + WS_WT;
  ushort* xb = (ushort*)(ws + WS_XB);
  ushort* Wtb = (ushort*)(ws + WS_WTB);
  float* temp = ws + WS_TEMP;
  float* rowDelta = ws + WS_DELTA;

  prep_kernel<<<2048, 256, 0, stream>>>(x, xb, W, Wt, Wtb);
  gemm_mfma_kernel<<<dim3(32, 32), 256, 0, stream>>>(xb, Wtb, h);
  softmax_kernel<<<2048, 256, 0, stream>>>(h, z, rowDelta);
  sample_fused_kernel<<<16384, 256, 0, stream>>>(z, rowDelta, x, Wt, oh, xd, temp);
  weight_kernel<<<8, 256, 0, stream>>>(temp, wo);
}

// Round 11
// 836.042 us; speedup vs baseline: 1.0766x; 1.0014x over previous
//
#include <hip/hip_runtime.h>
#include <stdint.h>
#include <math.h>

// Problem dims
static constexpr int BDIM = 2048;   // batch B
static constexpr int HDIM = 2048;   // hidden H
static constexpr int DDIM = 512;    // input dim D
static constexpr int NSAMP = 32;    // N_SAMPLE

// d_out layout (float elements, concatenated in return order)
static constexpr size_t OFF_H  = 0;
static constexpr size_t OFF_Z  = (size_t)BDIM * HDIM;                  // 4194304
static constexpr size_t OFF_OH = OFF_Z + (size_t)BDIM * HDIM;          // 8388608
static constexpr size_t OFF_XD = OFF_OH + (size_t)NSAMP * BDIM * HDIM; // 142606336
static constexpr size_t OFF_W  = OFF_XD + (size_t)NSAMP * BDIM * DDIM; // 176160768

// d_ws layout (float offsets): Wt fp32 [2048*512], xb bf16 [2048*512],
// Wtb bf16 [2048*512] (n-major), temp [65536], rowDelta [2048]
static constexpr size_t WS_WT    = 0;                          // 1048576 floats
static constexpr size_t WS_XB    = 1048576;                    // 524288 floats (1M ushort)
static constexpr size_t WS_WTB   = WS_XB + 524288;             // 524288 floats
static constexpr size_t WS_TEMP  = WS_WTB + 524288;
static constexpr size_t WS_DELTA = WS_TEMP + 65536;

typedef __attribute__((ext_vector_type(8))) short short8;
typedef __attribute__((ext_vector_type(4))) float f32x4;

__device__ __forceinline__ ushort f2bf(float f) {
  uint32_t x = __float_as_uint(f);
  return (ushort)((x + 0x7FFFu + ((x >> 16) & 1u)) >> 16);  // RNE, no NaN here
}

// ------- prep: [0,1024) transpose W -> Wt fp32 + Wtb bf16; [1024,2048) cast x
__global__ __launch_bounds__(256) void prep_kernel(const float* __restrict__ x,
                                                   ushort* __restrict__ xb,
                                                   const float* __restrict__ W,
                                                   float* __restrict__ Wt,
                                                   ushort* __restrict__ Wtb) {
  __shared__ float tile[32][33];
  if (blockIdx.x >= 1024) {
    // cast part: 1024 blocks x 256 threads x 4 floats = 1048576 elems
    const int i = ((blockIdx.x - 1024) * 256 + threadIdx.x) * 4;
    float4 v = *(const float4*)(x + i);
    ushort4 o = {f2bf(v.x), f2bf(v.y), f2bf(v.z), f2bf(v.w)};
    *(ushort4*)(xb + i) = o;
    return;
  }
  // transpose part (block-uniform branch, no divergence)
  const int tx = threadIdx.x & 31, ty = threadIdx.x >> 5;  // 32x8
  const int bx = blockIdx.x & 63;   // along H (2048/32=64)
  const int by = blockIdx.x >> 6;   // along D (512/32=16)
#pragma unroll
  for (int i = 0; i < 32; i += 8)
    tile[ty + i][tx] = W[(size_t)(by * 32 + ty + i) * HDIM + bx * 32 + tx];
  __syncthreads();
#pragma unroll
  for (int i = 0; i < 32; i += 8) {
    float v = tile[tx][ty + i];
    const size_t o = (size_t)(bx * 32 + ty + i) * DDIM + by * 32 + tx;
    Wt[o] = v;
    Wtb[o] = f2bf(v);
  }
}

// ---------------- GEMM: h = x @ W via bf16 MFMA (M=N=2048, K=512) -------------
// ROUND-7 VERSION (best measured config). A/B history: LDS-free +17,
// 128^2@1blk/CU +6 -> gemm ~10-40us, not the chain bottleneck.
__global__ __launch_bounds__(256, 4) void gemm_mfma_kernel(const ushort* __restrict__ xb,
                                                           const ushort* __restrict__ wtb,
                                                           float* __restrict__ h) {
  __shared__ short As[64][72];  // pad 8 shorts (16B) keeps b128 align, spreads banks
  __shared__ short Bs[64][72];
  const int tid = threadIdx.x;
  const int bm = blockIdx.y * 64, bn = blockIdx.x * 64;
  const int wave = tid >> 6, lane = tid & 63;
  const int wm = (wave >> 1) * 32, wn = (wave & 1) * 32;  // 2x2 waves of 32x32
  const int lrow = lane & 15, lk = (lane >> 4) * 8;

  f32x4 acc[2][2] = {};

  const int srow = tid >> 3;         // 0..31
  const int scol = (tid & 7) * 8;    // 0..56

  for (int k0 = 0; k0 < DDIM; k0 += 64) {
#pragma unroll
    for (int p = 0; p < 2; ++p) {
      const int r = srow + p * 32;
      short8 av = *(const short8*)(xb + (size_t)(bm + r) * DDIM + k0 + scol);
      short8 bv = *(const short8*)(wtb + (size_t)(bn + r) * DDIM + k0 + scol);
      *(short8*)&As[r][scol] = av;
      *(short8*)&Bs[r][scol] = bv;
    }
    __syncthreads();
#pragma unroll
    for (int kk = 0; kk < 64; kk += 32) {
      short8 af[2], bf[2];
#pragma unroll
      for (int i = 0; i < 2; ++i) {
        af[i] = *(const short8*)&As[wm + i * 16 + lrow][kk + lk];
        bf[i] = *(const short8*)&Bs[wn + i * 16 + lrow][kk + lk];
      }
#pragma unroll
      for (int i = 0; i < 2; ++i)
#pragma unroll
        for (int j = 0; j < 2; ++j)
          acc[i][j] = __builtin_amdgcn_mfma_f32_16x16x32_bf16(af[i], bf[j], acc[i][j], 0, 0, 0);
    }
    __syncthreads();
  }
#pragma unroll
  for (int i = 0; i < 2; ++i)
#pragma unroll
    for (int j = 0; j < 2; ++j)
#pragma unroll
      for (int rg = 0; rg < 4; ++rg) {
        const int row = bm + wm + i * 16 + (lane >> 4) * 4 + rg;
        const int col = bn + wn + j * 16 + (lane & 15);
        h[(size_t)row * HDIM + col] = acc[i][j][rg];
      }
}

// ---------------- Softmax rows + per-row z-spread (wave-shuffle, float4 I/O) --
__global__ __launch_bounds__(256) void softmax_kernel(const float* __restrict__ h,
                                                      float* __restrict__ z,
                                                      float* __restrict__ rowDelta) {
  const int b = blockIdx.x;
  const int tid = threadIdx.x;
  const int lane = tid & 63, wav = tid >> 6;
  const float* row = h + (size_t)b * HDIM;
  float* zrow = z + (size_t)b * HDIM;
  __shared__ float wmaxs[4], wmins[4], wsums[4];

  // each thread owns 8 contiguous floats -> 2 float4 loads, 32B/lane coalesced
  const float4 v0 = ((const float4*)row)[tid * 2];
  const float4 v1 = ((const float4*)row)[tid * 2 + 1];
  float vals[8] = {v0.x, v0.y, v0.z, v0.w, v1.x, v1.y, v1.z, v1.w};
  float vmax = -INFINITY, vmin = INFINITY;
#pragma unroll
  for (int k = 0; k < 8; ++k) {
    vmax = fmaxf(vmax, vals[k]);
    vmin = fminf(vmin, vals[k]);
  }
#pragma unroll
  for (int off = 32; off > 0; off >>= 1) {
    vmax = fmaxf(vmax, __shfl_xor(vmax, off, 64));
    vmin = fminf(vmin, __shfl_xor(vmin, off, 64));
  }
  if (lane == 0) { wmaxs[wav] = vmax; wmins[wav] = vmin; }
  __syncthreads();
  const float rmax = fmaxf(fmaxf(wmaxs[0], wmaxs[1]), fmaxf(wmaxs[2], wmaxs[3]));
  const float rmin = fminf(fminf(wmins[0], wmins[1]), fminf(wmins[2], wmins[3]));

  float e[8];
  float lsum = 0.f;
#pragma unroll
  for (int k = 0; k < 8; ++k) {
    e[k] = expf(vals[k] - rmax);
    lsum += e[k];
  }
#pragma unroll
  for (int off = 32; off > 0; off >>= 1) lsum += __shfl_xor(lsum, off, 64);
  if (lane == 0) wsums[wav] = lsum;
  __syncthreads();
  const float rsum = wsums[0] + wsums[1] + wsums[2] + wsums[3];
  const float rinv = 1.0f / rsum;
  float4 o0 = {e[0] * rinv, e[1] * rinv, e[2] * rinv, e[3] * rinv};
  float4 o1 = {e[4] * rinv, e[5] * rinv, e[6] * rinv, e[7] * rinv};
  ((float4*)zrow)[tid * 2] = o0;
  ((float4*)zrow)[tid * 2 + 1] = o1;
  if (tid == 0) rowDelta[b] = (1.0f - expf(rmin - rmax)) / rsum;  // z_max - z_min
}

// ---------------- Threefry-2x32, key = (0, 42) ----------------
// rotl forced to v_alignbit_b32 (funnel shift): alignbit(x,x,32-r) == rotl(x,r)
__device__ __forceinline__ uint32_t rotl_ab(uint32_t x, int r) {
  return __builtin_amdgcn_alignbit(x, x, 32 - r);
}
__device__ __forceinline__ void threefry_0_42(uint32_t x0, uint32_t x1,
                                              uint32_t& o0, uint32_t& o1) {
  const uint32_t ks0 = 0u, ks1 = 42u, ks2 = 0x1BD11BDAu ^ 0u ^ 42u;
  x0 += ks0; x1 += ks1;
#define TF_R(r) { x0 += x1; x1 = rotl_ab(x1, (r)); x1 ^= x0; }
  TF_R(13) TF_R(15) TF_R(26) TF_R(6)   x0 += ks1; x1 += ks2 + 1u;
  TF_R(17) TF_R(29) TF_R(16) TF_R(24)  x0 += ks2; x1 += ks0 + 2u;
  TF_R(13) TF_R(15) TF_R(26) TF_R(6)   x0 += ks0; x1 += ks1 + 3u;
  TF_R(17) TF_R(29) TF_R(16) TF_R(24)  x0 += ks1; x1 += ks2 + 4u;
  TF_R(13) TF_R(15) TF_R(26) TF_R(6)   x0 += ks2; x1 += ks0 + 5u;
#undef TF_R
  o0 = x0; o1 = x1;
}

// JAX uniform(tiny,1): u = ((bits>>9)|0x3f800000) as float - 1; 0 -> tiny
__device__ __forceinline__ float bits_to_u(uint32_t bits) {
  float f = __uint_as_float((bits >> 9) | 0x3f800000u) - 1.0f;
  return (f == 0.0f) ? 1.1754943508222875e-38f : f;
}

// ---- per-row sampler core: hash + screen + argmax (byte-identical logic to
// the verified round-7 code). Returns the sampled h index for flat row r.
__device__ __forceinline__ int sample_row(int r, int lane,
                                          const float* __restrict__ z,
                                          const float* __restrict__ rowDelta) {
  const int b = r & (BDIM - 1);
  const float dpad0 = rowDelta[b];

  const uint32_t base = (uint32_t)r << 11;
  uint32_t bb[32];
  uint32_t m23 = 0u;
#pragma unroll
  for (int k = 0; k < 32; ++k) {
    uint32_t o0, o1;
    threefry_0_42(0u, base + (uint32_t)(lane + (k << 6)), o0, o1);
    bb[k] = (o0 ^ o1) >> 9;
    m23 = max(m23, bb[k]);
  }
#pragma unroll
  for (int off = 32; off > 0; off >>= 1)
    m23 = max(m23, (uint32_t)__shfl_xor((int)m23, off, 64));
  const float umax = bits_to_u(m23 << 9);

  // conservative threshold: winner needs g(u) >= g(umax) - (zmax-zmin) - pad.
  // pad 3e-4 in g-space, -4 ulps u-space for libm slop, then to 23-bit space
  // (1+u has mantissa == bits>>9 exactly); m23-equality keeps row-max always in.
  const float dpad = dpad0 + 3e-4f;
  float uthr = expf(-expf(-(-logf(-logf(umax)) - dpad)));
  uthr = __uint_as_float(__float_as_uint(uthr) - 4u);
  uint32_t thr23 = __float_as_uint(1.0f + uthr) & 0x7FFFFFu;
  if (thr23 > 0u) thr23 -= 1u;  // absorb 1+uthr rounding

  uint32_t candMask = 0u;
#pragma unroll
  for (int k = 0; k < 32; ++k)
    if (bb[k] >= thr23 || bb[k] == m23) candMask |= (1u << k);

  int total = __popc(candMask);
  int myh = candMask ? (lane + ((__ffs(candMask) - 1) << 6)) : 0x7fffffff;
#pragma unroll
  for (int off = 32; off > 0; off >>= 1) {
    total += __shfl_xor(total, off, 64);
    myh = min(myh, __shfl_xor(myh, off, 64));
  }

  if (total == 1) return myh;  // single screen-passer is provably the argmax

  // exact path (rare, wave-uniform): rank candidates by double gumbel+z
  const float* zrow = z + (size_t)b * HDIM;
  double best = -1e300; int bh = 0x7fffffff;
#pragma unroll
  for (int k = 0; k < 32; ++k) {
    if (candMask & (1u << k)) {
      const int hh = lane + (k << 6);
      const float uk = bits_to_u(bb[k] << 9);
      double s = -log(-log((double)uk)) + (double)zrow[hh];
      if (s > best || (s == best && hh < bh)) { best = s; bh = hh; }
    }
  }
#pragma unroll
  for (int off = 32; off > 0; off >>= 1) {
    double so = __shfl_xor(best, off, 64);
    int ho = __shfl_xor(bh, off, 64);
    if (so > best || (so == best && ho < bh)) { best = so; bh = ho; }
  }
  return bh;
}

// write the onehot row for (j, bh): 8 coalesced f32x4 NT stores
__device__ __forceinline__ void store_oh_row(float* __restrict__ oh, int j,
                                             int bh, int lane) {
  f32x4* ohrow = (f32x4*)(oh + (size_t)j * HDIM);
#pragma unroll
  for (int k = 0; k < 8; ++k) {
    const int idx4 = (k << 6) + lane;
    const unsigned d = (unsigned)(bh - (idx4 << 2));
    f32x4 v;
    v.x = (d == 0u) ? 1.f : 0.f;
    v.y = (d == 1u) ? 1.f : 0.f;
    v.z = (d == 2u) ? 1.f : 0.f;
    v.w = (d == 3u) ? 1.f : 0.f;
    __builtin_nontemporal_store(v, &ohrow[idx4]);
  }
}

// xd row + temp from already-loaded wv/xv fragments
__device__ __forceinline__ void finish_row(float* __restrict__ xd,
                                           float* __restrict__ temp, int j,
                                           int lane, f32x4 wv0, f32x4 wv1,
                                           f32x4 xv0, f32x4 xv1) {
  f32x4* xdrow = (f32x4*)(xd + (size_t)j * DDIM);
  __builtin_nontemporal_store(wv0, &xdrow[lane]);
  __builtin_nontemporal_store(wv1, &xdrow[64 + lane]);
  float ss = 0.f;
  {
    const float dx = xv0.x - wv0.x, dy = xv0.y - wv0.y;
    const float dz = xv0.z - wv0.z, dw = xv0.w - wv0.w;
    ss += dx * dx + dy * dy + dz * dz + dw * dw;
  }
  {
    const float dx = xv1.x - wv1.x, dy = xv1.y - wv1.y;
    const float dz = xv1.z - wv1.z, dw = xv1.w - wv1.w;
    ss += dx * dx + dy * dy + dz * dz + dw * dw;
  }
#pragma unroll
  for (int off = 32; off > 0; off >>= 1) ss += __shfl_xor(ss, off, 64);
  if (lane == 0) temp[j] = 0.3989422804014327f * expf(-0.5f * ss);
}

// ---- FUSED sampler, SOFTWARE-PIPELINED 2 ROWS PER WAVE ----
// Theory (r6/r8/r10 calibration): VALU edits bite 0.26:1, memory edits 1:1 ->
// the sampler is memory-side bound. All waves are identical (2400cy pure-VALU
// hash then a 10KB store burst), so block generations stay PHASE-LOCKED: the
// machine alternates compute-phase <-> write-burst-phase and time adds up
// serially (hash ~135us + writes ~107us) instead of overlapping.
// Fix: each wave processes rows rA, rB. After argmax(A) it ISSUES A's Wt/x
// loads + 8 oh NT stores (no waits), then hashes B -- A's memory traffic
// drains under B's 2400-cycle hash. finish(A) afterwards (loads long since
// returned). Only B's tail is exposed. Held across hash(B): 4x f32x4 + bhA
// (~18 VGPR) on top of ~75 hash-live -> fits the (256,4) 128-VGPR cap.
__global__ __launch_bounds__(256, 4) void sample_fused_kernel(
    const float* __restrict__ z, const float* __restrict__ rowDelta,
    const float* __restrict__ x, const float* __restrict__ Wt,
    float* __restrict__ oh, float* __restrict__ xd, float* __restrict__ temp) {
  const int wav = threadIdx.x >> 6;
  const int lane = threadIdx.x & 63;
  const int rA = blockIdx.x * 8 + wav * 2;  // rows rA, rA+1 (0..65535)
  const int rB = rA + 1;

  // ---------- row A: hash + argmax ----------
  const int bhA = sample_row(rA, lane, z, rowDelta);

  // issue A's loads (L2/L3-resident) and oh stores; no waits -- they drain
  // under row B's hash phase.
  const int jA = ((rA & (BDIM - 1)) << 5) | (rA >> 11);
  const int cA = jA & (BDIM - 1);
  const f32x4* wrowA = (const f32x4*)(Wt + (size_t)bhA * DDIM);
  const f32x4* xrowA = (const f32x4*)(x + (size_t)cA * DDIM);
  const f32x4 wvA0 = wrowA[lane];
  const f32x4 wvA1 = wrowA[64 + lane];
  const f32x4 xvA0 = xrowA[lane];
  const f32x4 xvA1 = xrowA[64 + lane];
  store_oh_row(oh, jA, bhA, lane);

  // ---------- row B: hash + argmax (A's traffic in flight) ----------
  const int bhB = sample_row(rB, lane, z, rowDelta);

  // ---------- finish A (loads returned during B's hash) ----------
  finish_row(xd, temp, jA, lane, wvA0, wvA1, xvA0, xvA1);

  // ---------- row B outputs (tail exposed -- last in wave) ----------
  const int jB = ((rB & (BDIM - 1)) << 5) | (rB >> 11);
  const int cB = jB & (BDIM - 1);
  const f32x4* wrowB = (const f32x4*)(Wt + (size_t)bhB * DDIM);
  const f32x4* xrowB = (const f32x4*)(x + (size_t)cB * DDIM);
  const f32x4 wvB0 = wrowB[lane];
  const f32x4 wvB1 = wrowB[64 + lane];
  const f32x4 xvB0 = xrowB[lane];
  const f32x4 xvB1 = xrowB[64 + lane];
  store_oh_row(oh, jB, bhB, lane);
  finish_row(xd, temp, jB, lane, wvB0, wvB1, xvB0, xvB1);
}

// ---------------- weight = temp / mean_n(temp) ----------------
__global__ __launch_bounds__(256) void weight_kernel(const float* __restrict__ temp,
                                                     float* __restrict__ wout) {
  const int c = blockIdx.x * 256 + threadIdx.x;  // 0..2047
  if (c >= BDIM) return;
  float sum = 0.f;
#pragma unroll
  for (int a = 0; a < NSAMP; ++a) sum += temp[a * BDIM + c];
  const float mean = sum / 32.0f;
#pragma unroll
  for (int a = 0; a < NSAMP; ++a) wout[a * BDIM + c] = temp[a * BDIM + c] / mean;
}

extern "C" void kernel_launch(void* const* d_in, const int* in_sizes, int n_in,
                              void* d_out, int out_size, void* d_ws, size_t ws_size,
                              hipStream_t stream) {
  (void)in_sizes; (void)n_in; (void)out_size; (void)ws_size;
  const float* x = (const float*)d_in[0];  // [2048,512]
  const float* W = (const float*)d_in[1];  // [512,2048]
  float* out = (float*)d_out;

  float* h  = out + OFF_H;
  float* z  = out + OFF_Z;
  float* oh = out + OFF_OH;
  float* xd = out + OFF_XD;
  float* wo = out + OFF_W;

  float* ws = (float*)d_ws;
  float* Wt = ws + WS_WT;
  ushort* xb = (ushort*)(ws + WS_XB);
  ushort* Wtb = (ushort*)(ws + WS_WTB);
  float* temp = ws + WS_TEMP;
  float* rowDelta = ws + WS_DELTA;

  prep_kernel<<<2048, 256, 0, stream>>>(x, xb, W, Wt, Wtb);
  gemm_mfma_kernel<<<dim3(32, 32), 256, 0, stream>>>(xb, Wtb, h);
  softmax_kernel<<<2048, 256, 0, stream>>>(h, z, rowDelta);
  sample_fused_kernel<<<8192, 256, 0, stream>>>(z, rowDelta, x, Wt, oh, xd, temp);
  weight_kernel<<<8, 256, 0, stream>>>(temp, wo);
}